// Round 4
// baseline (161.368 us; speedup 1.0000x reference)
//
#include <hip/hip_runtime.h>
#include <hip/hip_bf16.h>

// Problem constants
#define S    2048
#define ND   128
#define NA   16
#define H    8
#define C    32
#define NH   24            // 3*H heads total
#define VD   128           // value dim per head
#define KQ_STRIDE (NH*C)   // 768 elems per row of K/Q
#define SCALE 0.3535533905932738f  // 1/sqrt(8)
#define NJS  2             // j-chunks (split-K over keys)

// bf16 conversion-buffer element counts (flat regions in ws)
#define AN_SZ (S*ND)        // nodes bf16          262144
#define AA_SZ (S*32)        // aux  bf16 K-pad 32   65536
#define BN_SZ (512*ND)      // Wn   bf16            65536
#define BA_SZ (512*32)      // Wa   bf16 K-pad 32   16384
#define BV_SZ (3072*ND)     // Wv   bf16           393216
#define CONV_TOTAL (AN_SZ + AA_SZ + BN_SZ + BA_SZ + BV_SZ)  // 802816

typedef __attribute__((ext_vector_type(8))) short short8;
typedef __attribute__((ext_vector_type(4))) short s4v;
typedef __attribute__((ext_vector_type(4))) float f32x4;

typedef __hip_bfloat16 bf16;

__device__ __forceinline__ short bf16_bits(float x) {
  bf16 h = __float2bfloat16(x);
  union { bf16 h; short s; } u; u.h = h; return u.s;
}

// ---------------------------------------------------------------------------
// Cast nodes/Wn/Wv to bf16; zero-pad aux/Wa from K=16 to K=32 (exact).
// ---------------------------------------------------------------------------
__global__ __launch_bounds__(256) void convert_kernel(
    const float* __restrict__ nodes, const float* __restrict__ aux,
    const float* __restrict__ Wn, const float* __restrict__ Wa,
    const float* __restrict__ Wv, bf16* __restrict__ out) {
  const int base = (blockIdx.x * 256 + threadIdx.x) * 4;
#pragma unroll
  for (int u = 0; u < 4; ++u) {
    const int idx = base + u;
    int k = idx;
    float v;
    if (k < AN_SZ) {
      v = nodes[k];
    } else if ((k -= AN_SZ) < AA_SZ) {
      const int ccol = k & 31;
      v = (ccol < 16) ? aux[(size_t)(k >> 5) * NA + ccol] : 0.0f;
    } else if ((k -= AA_SZ) < BN_SZ) {
      v = Wn[k];
    } else if ((k -= BN_SZ) < BA_SZ) {
      const int ccol = k & 31;
      v = (ccol < 16) ? Wa[(size_t)(k >> 5) * NA + ccol] : 0.0f;
    } else {
      v = Wv[k - BA_SZ];
    }
    out[idx] = __float2bfloat16(v);
  }
}

// ---------------------------------------------------------------------------
// MFMA projection GEMM (see R2 notes). EPI 0: nodes k/q; 1: aux k/q; 2: val^T.
// ---------------------------------------------------------------------------
template <int KE, int EPI>
__global__ __launch_bounds__(256) void gemm_proj_kernel(
    const bf16* __restrict__ A, const bf16* __restrict__ B,
    const float* __restrict__ bias,
    bf16* __restrict__ d0, bf16* __restrict__ d1) {
  const int t = threadIdx.x;
  const int lane = t & 63;
  const int w = t >> 6;
  const int l15 = lane & 15, g4 = lane >> 4;
  const int i0 = blockIdx.x * 64 + w * 16;
  const int o0 = blockIdx.y * 64;

  f32x4 acc[4];
#pragma unroll
  for (int s = 0; s < 4; ++s) acc[s] = (f32x4){0.f, 0.f, 0.f, 0.f};

  const bf16* arow = A + (size_t)(i0 + l15) * KE + g4 * 8;
  const bf16* brow = B + (size_t)(o0 + l15) * KE + g4 * 8;
#pragma unroll
  for (int ks = 0; ks < KE / 32; ++ks) {
    const short8 af = *reinterpret_cast<const short8*>(arow + ks * 32);
#pragma unroll
    for (int s = 0; s < 4; ++s) {
      const short8 bfr = *reinterpret_cast<const short8*>(
          brow + (size_t)s * 16 * KE + ks * 32);
      acc[s] = __builtin_amdgcn_mfma_f32_16x16x32_bf16(af, bfr, acc[s], 0, 0, 0);
    }
  }

#pragma unroll
  for (int s = 0; s < 4; ++s) {
    const int o = o0 + s * 16 + l15;
    const float bb = bias[o];
    if (EPI == 2) {
      s4v pk;
#pragma unroll
      for (int r = 0; r < 4; ++r) pk[r] = bf16_bits(acc[s][r] + bb);
      *reinterpret_cast<s4v*>(d0 + (size_t)o * S + i0 + g4 * 4) = pk;
    } else {
      const int head = (EPI == 0 ? 0 : 8) + (o >> 6);
      const int half = (o >> 5) & 1;
      const int c = o & 31;
      bf16* dst = half ? d1 : d0;
#pragma unroll
      for (int r = 0; r < 4; ++r)
        dst[(size_t)(i0 + g4 * 4 + r) * KQ_STRIDE + head * C + c] =
            __float2bfloat16(acc[s][r] + bb);
    }
  }
}

// ---------------------------------------------------------------------------
// Rot-head rank-4 precompute: M_h = W_rk_h^T W_rq_h, G[i][h][:] = rot_i^T M_h
// ---------------------------------------------------------------------------
__global__ __launch_bounds__(256) void rotg_kernel(
    const float* __restrict__ rot, const float* __restrict__ Wr,
    float* __restrict__ G) {
  __shared__ float M[8][4][4];
  const int t = threadIdx.x;
  if (t < 128) {
    const int hl = t >> 4, a = (t >> 2) & 3, b = t & 3;
    float s = 0.0f;
#pragma unroll
    for (int c = 0; c < 32; ++c)
      s += Wr[(size_t)(hl * 64 + c) * 4 + a] * Wr[(size_t)(hl * 64 + 32 + c) * 4 + b];
    M[hl][a][b] = s;
  }
  __syncthreads();
  const int i  = blockIdx.x * 32 + (t >> 3);
  const int hl = t & 7;
  const float4 rv = *reinterpret_cast<const float4*>(rot + (size_t)i * 4);
  float4 g;
  g.x = rv.x * M[hl][0][0] + rv.y * M[hl][1][0] + rv.z * M[hl][2][0] + rv.w * M[hl][3][0];
  g.y = rv.x * M[hl][0][1] + rv.y * M[hl][1][1] + rv.z * M[hl][2][1] + rv.w * M[hl][3][1];
  g.z = rv.x * M[hl][0][2] + rv.y * M[hl][1][2] + rv.z * M[hl][2][2] + rv.w * M[hl][3][2];
  g.w = rv.x * M[hl][0][3] + rv.y * M[hl][1][3] + rv.z * M[hl][2][3] + rv.w * M[hl][3][3];
  *reinterpret_cast<float4*>(G + ((size_t)i * 8 + hl) * 4) = g;
}

// ---------------------------------------------------------------------------
// MFMA flash attention over a j-chunk.
// MODE 0: split-K — write unnormalized O to Op[js] and (m,l) to Ml[js].
// MODE 1: single chunk — write normalized per-head O to Op (reduce later).
// MODE 2: single chunk — atomicAdd normalized O into out directly.
// Vs is XOR-swizzled (elem ^= (row&7)<<3) so no pad: LDS = 16K + 9.2K.
// ---------------------------------------------------------------------------
#define VS(d, e) ((d) * 64 + ((e) ^ (((d) & 7) << 3)))

template <int MODE>
__global__ __launch_bounds__(256) void attn_mfma_kernel(
    const bf16* __restrict__ Kb, const bf16* __restrict__ Qb,
    const bf16* __restrict__ Vt, const float* __restrict__ G,
    const float* __restrict__ rot, float* __restrict__ Op,
    float* __restrict__ Ml, int jchunk) {
  const int h    = blockIdx.y;
  const int i0   = blockIdx.x * 64;
  const int js   = blockIdx.z;
  const int t    = threadIdx.x;
  const int lane = t & 63;
  const int w    = t >> 6;
  const int l15  = lane & 15;
  const int g4   = lane >> 4;
  const bool isrot = (h >= 16);
  const int jbeg = js * jchunk;
  const int jend = jbeg + jchunk;

  __shared__ __align__(16) bf16 Vs[128 * 64];    // XOR-swizzled [d][j]
  __shared__ __align__(16) bf16 Ps[4][16][72];   // per-wave P tile [i][j], padded

  short8 kfrag = {0, 0, 0, 0, 0, 0, 0, 0};
  float grow[4][4];
  if (!isrot) {
    kfrag = *reinterpret_cast<const short8*>(
        Kb + (size_t)(i0 + w * 16 + l15) * KQ_STRIDE + h * C + g4 * 8);
  } else {
    const int hl = h - 16;
#pragma unroll
    for (int r = 0; r < 4; ++r) {
      const float4 gv = *reinterpret_cast<const float4*>(
          G + ((size_t)(i0 + w * 16 + g4 * 4 + r) * 8 + hl) * 4);
      grow[r][0] = gv.x; grow[r][1] = gv.y; grow[r][2] = gv.z; grow[r][3] = gv.w;
    }
  }

  float m[4], l[4];
  f32x4 oacc[8];
#pragma unroll
  for (int r = 0; r < 4; ++r) { m[r] = -1e30f; l[r] = 0.0f; }
#pragma unroll
  for (int d = 0; d < 8; ++d) oacc[d] = (f32x4){0.f, 0.f, 0.f, 0.f};

  for (int j0 = jbeg; j0 < jend; j0 += 64) {
    // ---- stage V tile (swizzled) ----
    {
      const int d  = t >> 1;
      const int jh = (t & 1) * 32;
      const bf16* src = Vt + ((size_t)h * VD + d) * S + j0 + jh;
#pragma unroll
      for (int c = 0; c < 4; ++c) {
        short8 v = *reinterpret_cast<const short8*>(src + c * 8);
        *reinterpret_cast<short8*>(&Vs[VS(d, jh + c * 8)]) = v;
      }
    }
    __syncthreads();

    // ---- scores ----
    f32x4 sf[4];
    if (!isrot) {
#pragma unroll
      for (int sub = 0; sub < 4; ++sub) {
        short8 qf = *reinterpret_cast<const short8*>(
            Qb + (size_t)(j0 + sub * 16 + l15) * KQ_STRIDE + h * C + g4 * 8);
        f32x4 z = {0.f, 0.f, 0.f, 0.f};
        sf[sub] = __builtin_amdgcn_mfma_f32_16x16x32_bf16(kfrag, qf, z, 0, 0, 0);
#pragma unroll
        for (int r = 0; r < 4; ++r) sf[sub][r] *= SCALE;
      }
    } else {
#pragma unroll
      for (int sub = 0; sub < 4; ++sub) {
        const float4 rv = *reinterpret_cast<const float4*>(
            rot + (size_t)(j0 + sub * 16 + l15) * 4);
#pragma unroll
        for (int r = 0; r < 4; ++r) {
          float s = grow[r][0] * rv.x + grow[r][1] * rv.y
                  + grow[r][2] * rv.z + grow[r][3] * rv.w;
          sf[sub][r] = s * s * SCALE;
        }
      }
    }

    // ---- tile max per row ----
    float tm[4];
#pragma unroll
    for (int r = 0; r < 4; ++r) {
      float v = fmaxf(fmaxf(sf[0][r], sf[1][r]), fmaxf(sf[2][r], sf[3][r]));
      v = fmaxf(v, __shfl_xor(v, 1));
      v = fmaxf(v, __shfl_xor(v, 2));
      v = fmaxf(v, __shfl_xor(v, 4));
      v = fmaxf(v, __shfl_xor(v, 8));
      tm[r] = v;
    }
    // ---- rescale only if some row's max grew (exact skip: corr==1) ----
    const bool need = (tm[0] > m[0]) | (tm[1] > m[1]) |
                      (tm[2] > m[2]) | (tm[3] > m[3]);
    if (__any(need)) {
#pragma unroll
      for (int r = 0; r < 4; ++r) {
        const float mnew = fmaxf(m[r], tm[r]);
        const float corr = __expf(m[r] - mnew);
        m[r] = mnew;
        l[r] *= corr;
#pragma unroll
        for (int d = 0; d < 8; ++d) oacc[d][r] *= corr;
      }
    }
    // ---- exp + row-sum + P store ----
#pragma unroll
    for (int r = 0; r < 4; ++r) {
      float ls = 0.0f;
#pragma unroll
      for (int sub = 0; sub < 4; ++sub) {
        float p = __expf(sf[sub][r] - m[r]);
        sf[sub][r] = p;
        ls += p;
      }
      ls += __shfl_xor(ls, 1);
      ls += __shfl_xor(ls, 2);
      ls += __shfl_xor(ls, 4);
      ls += __shfl_xor(ls, 8);
      l[r] += ls;
#pragma unroll
      for (int sub = 0; sub < 4; ++sub)
        Ps[w][g4 * 4 + r][sub * 16 + l15] = __float2bfloat16(sf[sub][r]);
    }

    // ---- PV ----
#pragma unroll
    for (int kh = 0; kh < 2; ++kh) {
      const short8 pa = *reinterpret_cast<const short8*>(&Ps[w][l15][kh * 32 + g4 * 8]);
#pragma unroll
      for (int dsub = 0; dsub < 8; ++dsub) {
        const short8 vb = *reinterpret_cast<const short8*>(
            &Vs[VS(dsub * 16 + l15, kh * 32 + g4 * 8)]);
        oacc[dsub] = __builtin_amdgcn_mfma_f32_16x16x32_bf16(pa, vb, oacc[dsub], 0, 0, 0);
      }
    }
    __syncthreads();
  }

  if (MODE == 0) {
    float* op = Op + ((size_t)js * NH + h) * (size_t)S * VD;
#pragma unroll
    for (int dsub = 0; dsub < 8; ++dsub)
#pragma unroll
      for (int r = 0; r < 4; ++r)
        op[(size_t)(i0 + w * 16 + g4 * 4 + r) * VD + dsub * 16 + l15] =
            oacc[dsub][r];
    if (l15 == 0) {
#pragma unroll
      for (int r = 0; r < 4; ++r) {
        const size_t idx = (((size_t)js * NH + h) * S + i0 + w * 16 + g4 * 4 + r) * 2;
        Ml[idx]     = m[r];
        Ml[idx + 1] = l[r];
      }
    }
  } else {
    float inv[4];
#pragma unroll
    for (int r = 0; r < 4; ++r) inv[r] = 1.0f / l[r];
    if (MODE == 2) {
#pragma unroll
      for (int dsub = 0; dsub < 8; ++dsub)
#pragma unroll
        for (int r = 0; r < 4; ++r)
          atomicAdd(Op + (size_t)(i0 + w * 16 + g4 * 4 + r) * VD + dsub * 16 + l15,
                    oacc[dsub][r] * inv[r]);
    } else {
      float* op = Op + (size_t)h * (S * VD);
#pragma unroll
      for (int dsub = 0; dsub < 8; ++dsub)
#pragma unroll
        for (int r = 0; r < 4; ++r)
          op[(size_t)(i0 + w * 16 + g4 * 4 + r) * VD + dsub * 16 + l15] =
              oacc[dsub][r] * inv[r];
    }
  }
}

// ---------------------------------------------------------------------------
// Combine NJS j-chunk partials and sum heads: out[i][d].
// ---------------------------------------------------------------------------
__global__ __launch_bounds__(256) void combine_kernel(
    const float* __restrict__ Op, const float* __restrict__ Ml,
    float* __restrict__ out) {
  const int idx = blockIdx.x * 256 + threadIdx.x;  // S*VD
  const int i = idx >> 7;
  const int d = idx & 127;
  float s = 0.0f;
#pragma unroll
  for (int h = 0; h < NH; ++h) {
    const size_t b0 = ((size_t)0 * NH + h) * S + i;
    const size_t b1 = ((size_t)1 * NH + h) * S + i;
    const float m0 = Ml[b0 * 2], l0 = Ml[b0 * 2 + 1];
    const float m1 = Ml[b1 * 2], l1 = Ml[b1 * 2 + 1];
    const float M = fmaxf(m0, m1);
    const float w0 = __expf(m0 - M), w1 = __expf(m1 - M);
    const float num = w0 * Op[b0 * VD + d] + w1 * Op[b1 * VD + d];
    s += num / (w0 * l0 + w1 * l1);
  }
  out[idx] = s;
}

// Sum the 24 per-head partials into the final (S, 128) output (MODE 1 path).
__global__ __launch_bounds__(256) void reduce_out_kernel(
    const float* __restrict__ OP, float* __restrict__ out) {
  const int idx = blockIdx.x * 256 + threadIdx.x;
  float s = 0.0f;
#pragma unroll
  for (int hh = 0; hh < NH; ++hh) s += OP[(size_t)hh * (S * VD) + idx];
  out[idx] = s;
}

extern "C" void kernel_launch(void* const* d_in, const int* in_sizes, int n_in,
                              void* d_out, int out_size, void* d_ws, size_t ws_size,
                              hipStream_t stream) {
  const float* nodes = (const float*)d_in[0];
  const float* aux   = (const float*)d_in[1];
  const float* rot   = (const float*)d_in[2];
  const float* Wn    = (const float*)d_in[3];
  const float* bn    = (const float*)d_in[4];
  const float* Wa    = (const float*)d_in[5];
  const float* ba    = (const float*)d_in[6];
  const float* Wr    = (const float*)d_in[7];
  const float* Wv    = (const float*)d_in[8];
  const float* bv    = (const float*)d_in[9];
  float* out = (float*)d_out;

  char* ws = (char*)d_ws;
  const size_t off_conv = 0;                                    // bf16 x 802816
  const size_t off_Kb   = off_conv + (size_t)CONV_TOTAL * 2;
  const size_t off_Qb   = off_Kb + (size_t)S * KQ_STRIDE * 2;
  const size_t off_Vt   = off_Qb + (size_t)S * KQ_STRIDE * 2;
  const size_t off_G    = off_Vt + (size_t)NH * VD * S * 2;
  const size_t off_Op   = off_G + (size_t)S * 8 * 4 * 4;
  const size_t off_Ml   = off_Op + (size_t)NJS * NH * S * VD * 4;   // 50.3 MB
  const size_t need2    = off_Ml + (size_t)NJS * NH * S * 2 * 4;    // ~72 MB
  const size_t need1    = off_Op + (size_t)NH * S * VD * 4;         // ~46 MB

  bf16* convb = (bf16*)(ws + off_conv);
  bf16* An = convb;
  bf16* Aa = convb + AN_SZ;
  bf16* Bn = convb + AN_SZ + AA_SZ;
  bf16* Ba = convb + AN_SZ + AA_SZ + BN_SZ;
  bf16* Bv = convb + AN_SZ + AA_SZ + BN_SZ + BA_SZ;
  bf16*  Kb = (bf16*)(ws + off_Kb);
  bf16*  Qb = (bf16*)(ws + off_Qb);
  bf16*  Vt = (bf16*)(ws + off_Vt);
  float* G  = (float*)(ws + off_G);
  float* Op = (float*)(ws + off_Op);
  float* Ml = (float*)(ws + off_Ml);

  convert_kernel<<<CONV_TOTAL / 1024, 256, 0, stream>>>(nodes, aux, Wn, Wa, Wv, convb);
  rotg_kernel<<<S / 32, 256, 0, stream>>>(rot, Wr, G);

  gemm_proj_kernel<128, 0><<<dim3(S / 64, 512 / 64), 256, 0, stream>>>(
      An, Bn, bn, Kb, Qb);
  gemm_proj_kernel<32, 1><<<dim3(S / 64, 512 / 64), 256, 0, stream>>>(
      Aa, Ba, ba, Kb, Qb);
  gemm_proj_kernel<128, 2><<<dim3(S / 64, 3072 / 64), 256, 0, stream>>>(
      An, Bv, bv, Vt, nullptr);

  if (ws_size >= need2) {
    attn_mfma_kernel<0><<<dim3(S / 64, NH, NJS), 256, 0, stream>>>(
        Kb, Qb, Vt, G, rot, Op, Ml, S / NJS);
    combine_kernel<<<(S * VD) / 256, 256, 0, stream>>>(Op, Ml, out);
  } else if (ws_size >= need1) {
    attn_mfma_kernel<1><<<dim3(S / 64, NH, 1), 256, 0, stream>>>(
        Kb, Qb, Vt, G, rot, Op, nullptr, S);
    reduce_out_kernel<<<(S * VD) / 256, 256, 0, stream>>>(Op, out);
  } else {
    hipMemsetAsync(d_out, 0, (size_t)out_size * sizeof(float), stream);
    attn_mfma_kernel<2><<<dim3(S / 64, NH, 1), 256, 0, stream>>>(
        Kb, Qb, Vt, G, rot, out, nullptr, S);
  }
}

// Round 5
// 127.052 us; speedup vs baseline: 1.2701x; 1.2701x over previous
//
#include <hip/hip_runtime.h>
#include <hip/hip_bf16.h>

// Problem constants
#define S    2048
#define ND   128
#define NA   16
#define H    8
#define C    32
#define NH   24            // 3*H heads total
#define VD   128           // value dim per head
#define KQ_STRIDE (NH*C)   // 768 elems per row of K/Q
#define SCALE 0.3535533905932738f   // 1/sqrt(8)
#define SQS   0.5946035575013605f   // sqrt(SCALE)

// bf16 conversion-buffer element counts (flat regions in ws)
#define AN_SZ (S*ND)        // nodes bf16          262144
#define AA_SZ (S*32)        // aux  bf16 K-pad 32   65536
#define BN_SZ (512*ND)      // Wn   bf16            65536
#define BA_SZ (512*32)      // Wa   bf16 K-pad 32   16384
#define BV_SZ (3072*ND)     // Wv   bf16           393216
#define CONV_TOTAL (AN_SZ + AA_SZ + BN_SZ + BA_SZ + BV_SZ)  // 802816

typedef __attribute__((ext_vector_type(8))) short short8;
typedef __attribute__((ext_vector_type(4))) short s4v;
typedef __attribute__((ext_vector_type(4))) float f32x4;

typedef __hip_bfloat16 bf16;

__device__ __forceinline__ short bf16_bits(float x) {
  bf16 h = __float2bfloat16(x);
  union { bf16 h; short s; } u; u.h = h; return u.s;
}

// ---------------------------------------------------------------------------
// Cast nodes/Wn/Wv to bf16; zero-pad aux/Wa from K=16 to K=32 (exact).
// ---------------------------------------------------------------------------
__global__ __launch_bounds__(256) void convert_kernel(
    const float* __restrict__ nodes, const float* __restrict__ aux,
    const float* __restrict__ Wn, const float* __restrict__ Wa,
    const float* __restrict__ Wv, bf16* __restrict__ out) {
  const int base = (blockIdx.x * 256 + threadIdx.x) * 4;
#pragma unroll
  for (int u = 0; u < 4; ++u) {
    const int idx = base + u;
    int k = idx;
    float v;
    if (k < AN_SZ) {
      v = nodes[k];
    } else if ((k -= AN_SZ) < AA_SZ) {
      const int ccol = k & 31;
      v = (ccol < 16) ? aux[(size_t)(k >> 5) * NA + ccol] : 0.0f;
    } else if ((k -= AA_SZ) < BN_SZ) {
      v = Wn[k];
    } else if ((k -= BN_SZ) < BA_SZ) {
      const int ccol = k & 31;
      v = (ccol < 16) ? Wa[(size_t)(k >> 5) * NA + ccol] : 0.0f;
    } else {
      v = Wv[k - BA_SZ];
    }
    out[idx] = __float2bfloat16(v);
  }
}

// ---------------------------------------------------------------------------
// MFMA projection GEMM. EPI 0: nodes k/q (K scaled by SCALE); 1: aux k/q
// (K scaled); 2: val^T. A rows i, B rows o; D[i][o].
// ---------------------------------------------------------------------------
template <int KE, int EPI>
__global__ __launch_bounds__(256) void gemm_proj_kernel(
    const bf16* __restrict__ A, const bf16* __restrict__ B,
    const float* __restrict__ bias,
    bf16* __restrict__ d0, bf16* __restrict__ d1) {
  const int t = threadIdx.x;
  const int lane = t & 63;
  const int w = t >> 6;
  const int l15 = lane & 15, g4 = lane >> 4;
  const int i0 = blockIdx.x * 64 + w * 16;
  const int o0 = blockIdx.y * 64;

  f32x4 acc[4];
#pragma unroll
  for (int s = 0; s < 4; ++s) acc[s] = (f32x4){0.f, 0.f, 0.f, 0.f};

  const bf16* arow = A + (size_t)(i0 + l15) * KE + g4 * 8;
  const bf16* brow = B + (size_t)(o0 + l15) * KE + g4 * 8;
#pragma unroll
  for (int ks = 0; ks < KE / 32; ++ks) {
    const short8 af = *reinterpret_cast<const short8*>(arow + ks * 32);
#pragma unroll
    for (int s = 0; s < 4; ++s) {
      const short8 bfr = *reinterpret_cast<const short8*>(
          brow + (size_t)s * 16 * KE + ks * 32);
      acc[s] = __builtin_amdgcn_mfma_f32_16x16x32_bf16(af, bfr, acc[s], 0, 0, 0);
    }
  }

#pragma unroll
  for (int s = 0; s < 4; ++s) {
    const int o = o0 + s * 16 + l15;
    const float bb = bias[o];
    if (EPI == 2) {
      s4v pk;
#pragma unroll
      for (int r = 0; r < 4; ++r) pk[r] = bf16_bits(acc[s][r] + bb);
      *reinterpret_cast<s4v*>(d0 + (size_t)o * S + i0 + g4 * 4) = pk;
    } else {
      const int head = (EPI == 0 ? 0 : 8) + (o >> 6);
      const int half = (o >> 5) & 1;
      const int c = o & 31;
      bf16* dst = half ? d1 : d0;
      const float sc = half ? 1.0f : SCALE;  // fold SCALE into K
#pragma unroll
      for (int r = 0; r < 4; ++r)
        dst[(size_t)(i0 + g4 * 4 + r) * KQ_STRIDE + head * C + c] =
            __float2bfloat16((acc[s][r] + bb) * sc);
    }
  }
}

// ---------------------------------------------------------------------------
// Rot-head precompute. M_h = (W_rk_h^T W_rq_h)*sqrt(SCALE); G_i = rot_i^T M_h.
// Emit bf16 hi/lo splits so rot scores run on the SAME MFMA path:
//   Ghat[i] = [Ghi(4), Glo(4), Ghi(4), 0*20]
//   Rhat[j] = [rhi(4), rhi(4), rlo(4), 0*20]
//   Ghat.Rhat = Ghi.rhi + Glo.rhi + Ghi.rlo ~= G.r  (err ~1e-5 rel)
// ---------------------------------------------------------------------------
__global__ __launch_bounds__(256) void rotg_kernel(
    const float* __restrict__ rot, const float* __restrict__ Wr,
    bf16* __restrict__ Ghat, bf16* __restrict__ Rhat) {
  __shared__ float M[8][4][4];
  const int t = threadIdx.x;
  if (t < 128) {
    const int hl = t >> 4, a = (t >> 2) & 3, b = t & 3;
    float s = 0.0f;
#pragma unroll
    for (int c = 0; c < 32; ++c)
      s += Wr[(size_t)(hl * 64 + c) * 4 + a] * Wr[(size_t)(hl * 64 + 32 + c) * 4 + b];
    M[hl][a][b] = s * SQS;
  }
  __syncthreads();
  const int i  = blockIdx.x * 32 + (t >> 3);
  const int hl = t & 7;
  const float4 rv = *reinterpret_cast<const float4*>(rot + (size_t)i * 4);
  float g[4];
#pragma unroll
  for (int b = 0; b < 4; ++b)
    g[b] = rv.x * M[hl][0][b] + rv.y * M[hl][1][b]
         + rv.z * M[hl][2][b] + rv.w * M[hl][3][b];

  short hi[4], lo[4];
#pragma unroll
  for (int b = 0; b < 4; ++b) {
    bf16 hb = __float2bfloat16(g[b]);
    hi[b] = bf16_bits(g[b]);
    lo[b] = bf16_bits(g[b] - __bfloat162float(hb));
  }
  const short8 zz = {0, 0, 0, 0, 0, 0, 0, 0};
  short8 w0 = {hi[0], hi[1], hi[2], hi[3], lo[0], lo[1], lo[2], lo[3]};
  short8 w1 = {hi[0], hi[1], hi[2], hi[3], 0, 0, 0, 0};
  bf16* gp = Ghat + ((size_t)hl * S + i) * 32;
  *reinterpret_cast<short8*>(gp)      = w0;
  *reinterpret_cast<short8*>(gp + 8)  = w1;
  *reinterpret_cast<short8*>(gp + 16) = zz;
  *reinterpret_cast<short8*>(gp + 24) = zz;

  if (hl == 0) {
    float rr[4] = {rv.x, rv.y, rv.z, rv.w};
    short rh[4], rl[4];
#pragma unroll
    for (int b = 0; b < 4; ++b) {
      bf16 hb = __float2bfloat16(rr[b]);
      rh[b] = bf16_bits(rr[b]);
      rl[b] = bf16_bits(rr[b] - __bfloat162float(hb));
    }
    short8 r0 = {rh[0], rh[1], rh[2], rh[3], rh[0], rh[1], rh[2], rh[3]};
    short8 r1 = {rl[0], rl[1], rl[2], rl[3], 0, 0, 0, 0};
    bf16* rp = Rhat + (size_t)i * 32;
    *reinterpret_cast<short8*>(rp)      = r0;
    *reinterpret_cast<short8*>(rp + 8)  = r1;
    *reinterpret_cast<short8*>(rp + 16) = zz;
    *reinterpret_cast<short8*>(rp + 24) = zz;
  }
}

// ---------------------------------------------------------------------------
// Swapped-layout MFMA flash attention.
// QK^T as mfma(Q,K) -> S^T[j][i]: lane owns ONE i-row (i = l15), 16 j vals
// in regs (j = sub*16 + g4*4 + r). Softmax: 15 in-reg max/add + 2 shfl.
// P packed j-contiguous via v_cvt_pk_bf16_f32 -> 4 ds_write_b64; PV B-frag
// read back as 2 ds_read_b128. PV as O^T = V^T * P^T (V tiles unchanged).
// V double-buffered, async-stage split: loads issued a tile early, LDS
// write right after the single per-tile barrier.
// MODE 1: per-head O to Op (reduce later). MODE 2: atomicAdd into out.
// ---------------------------------------------------------------------------
#define VS(d, e) ((d) * 64 + ((e) ^ (((d) & 7) << 3)))

template <int MODE>
__global__ __launch_bounds__(256) void attn_mfma_kernel(
    const bf16* __restrict__ Kb, const bf16* __restrict__ Qb,
    const bf16* __restrict__ Vt, const bf16* __restrict__ Ghat,
    const bf16* __restrict__ Rhat, float* __restrict__ Op) {
  const int h    = blockIdx.y;
  const int i0   = blockIdx.x * 64;
  const int t    = threadIdx.x;
  const int lane = t & 63;
  const int w    = t >> 6;
  const int l15  = lane & 15;
  const int g4   = lane >> 4;
  const bool isrot = (h >= 16);

  __shared__ __align__(16) bf16 Vs[2][128 * 64];          // 32 KB, swizzled
  __shared__ __align__(16) unsigned int Ps[4][16][40];    // 10 KB, P words

  const bf16* kp; const bf16* qp; int kst, qst;
  if (!isrot) {
    kp = Kb + h * C; qp = Qb + h * C; kst = KQ_STRIDE; qst = KQ_STRIDE;
  } else {
    kp = Ghat + (size_t)(h - 16) * S * 32; qp = Rhat; kst = 32; qst = 32;
  }

  // B-frag: K row for this wave's i = i0 + w*16 + l15
  const short8 kfrag = *reinterpret_cast<const short8*>(
      kp + (size_t)(i0 + w * 16 + l15) * kst + g4 * 8);

  float m = -1e30f, l = 0.0f;
  f32x4 oacc[8];
#pragma unroll
  for (int d = 0; d < 8; ++d) oacc[d] = (f32x4){0.f, 0.f, 0.f, 0.f};

  // V staging: thread owns (row d = t>>1, 32-elem half jh)
  const int vd  = t >> 1;
  const int vjh = (t & 1) * 32;
  const bf16* vsrc = Vt + ((size_t)h * VD + vd) * S + vjh;
  short8 vr0, vr1, vr2, vr3;

  // prologue: V(0) -> LDS0; V(1) -> regs
  vr0 = *reinterpret_cast<const short8*>(vsrc);
  vr1 = *reinterpret_cast<const short8*>(vsrc + 8);
  vr2 = *reinterpret_cast<const short8*>(vsrc + 16);
  vr3 = *reinterpret_cast<const short8*>(vsrc + 24);
  {
    bf16* dst = &Vs[0][0];
    *reinterpret_cast<short8*>(&dst[VS(vd, vjh)])      = vr0;
    *reinterpret_cast<short8*>(&dst[VS(vd, vjh + 8)])  = vr1;
    *reinterpret_cast<short8*>(&dst[VS(vd, vjh + 16)]) = vr2;
    *reinterpret_cast<short8*>(&dst[VS(vd, vjh + 24)]) = vr3;
  }
  vr0 = *reinterpret_cast<const short8*>(vsrc + 64);
  vr1 = *reinterpret_cast<const short8*>(vsrc + 72);
  vr2 = *reinterpret_cast<const short8*>(vsrc + 80);
  vr3 = *reinterpret_cast<const short8*>(vsrc + 88);

  int cur = 0;
  for (int j0 = 0; j0 < S; j0 += 64) {
    __syncthreads();
    // T14 write-late: commit prefetched V(t+1), then issue V(t+2) loads
    if (j0 + 64 < S) {
      bf16* dst = &Vs[cur ^ 1][0];
      *reinterpret_cast<short8*>(&dst[VS(vd, vjh)])      = vr0;
      *reinterpret_cast<short8*>(&dst[VS(vd, vjh + 8)])  = vr1;
      *reinterpret_cast<short8*>(&dst[VS(vd, vjh + 16)]) = vr2;
      *reinterpret_cast<short8*>(&dst[VS(vd, vjh + 24)]) = vr3;
      if (j0 + 128 < S) {
        const bf16* p = vsrc + j0 + 128;
        vr0 = *reinterpret_cast<const short8*>(p);
        vr1 = *reinterpret_cast<const short8*>(p + 8);
        vr2 = *reinterpret_cast<const short8*>(p + 16);
        vr3 = *reinterpret_cast<const short8*>(p + 24);
      }
    }

    // ---- scores S^T[j][i]: lane holds j = sub*16 + g4*4 + r, i = l15 ----
    f32x4 sf[4];
#pragma unroll
    for (int sub = 0; sub < 4; ++sub) {
      const short8 qf = *reinterpret_cast<const short8*>(
          qp + (size_t)(j0 + sub * 16 + l15) * qst + g4 * 8);
      f32x4 z = {0.f, 0.f, 0.f, 0.f};
      sf[sub] = __builtin_amdgcn_mfma_f32_16x16x32_bf16(qf, kfrag, z, 0, 0, 0);
    }
    if (isrot) {
#pragma unroll
      for (int sub = 0; sub < 4; ++sub)
#pragma unroll
        for (int r = 0; r < 4; ++r) sf[sub][r] *= sf[sub][r];
    }

    // ---- online softmax over j (16 regs + g4 groups) ----
    float tm = sf[0][0];
#pragma unroll
    for (int sub = 0; sub < 4; ++sub)
#pragma unroll
      for (int r = 0; r < 4; ++r) tm = fmaxf(tm, sf[sub][r]);
    tm = fmaxf(tm, __shfl_xor(tm, 16));
    tm = fmaxf(tm, __shfl_xor(tm, 32));
    if (__any(tm > m)) {
      const float mnew = fmaxf(m, tm);
      const float corr = __expf(m - mnew);
      m = mnew;
      l *= corr;
#pragma unroll
      for (int d = 0; d < 8; ++d)
#pragma unroll
        for (int r = 0; r < 4; ++r) oacc[d][r] *= corr;
    }
    float ls = 0.0f;
#pragma unroll
    for (int sub = 0; sub < 4; ++sub)
#pragma unroll
      for (int r = 0; r < 4; ++r) {
        const float p = __expf(sf[sub][r] - m);
        sf[sub][r] = p;
        ls += p;
      }
    ls += __shfl_xor(ls, 16);
    ls += __shfl_xor(ls, 32);
    l += ls;

    // ---- pack P -> bf16 pairs, store 4x ds_write_b64 ----
#pragma unroll
    for (int sub = 0; sub < 4; ++sub) {
      unsigned int u0, u1;
      asm volatile("v_cvt_pk_bf16_f32 %0, %1, %2"
                   : "=v"(u0) : "v"(sf[sub][0]), "v"(sf[sub][1]));
      asm volatile("v_cvt_pk_bf16_f32 %0, %1, %2"
                   : "=v"(u1) : "v"(sf[sub][2]), "v"(sf[sub][3]));
      uint2 pk; pk.x = u0; pk.y = u1;
      *reinterpret_cast<uint2*>(&Ps[w][l15][sub * 8 + g4 * 2]) = pk;
    }

    // ---- PV: O^T[d][i] += V^T[d][j] P[i][j] ----
#pragma unroll
    for (int kh = 0; kh < 2; ++kh) {
      union { uint4 u; short8 s; } pb;
      pb.u = *reinterpret_cast<const uint4*>(&Ps[w][l15][kh * 16 + g4 * 4]);
#pragma unroll
      for (int dsub = 0; dsub < 8; ++dsub) {
        const short8 vb = *reinterpret_cast<const short8*>(
            &Vs[cur][VS(dsub * 16 + l15, kh * 32 + g4 * 8)]);
        oacc[dsub] =
            __builtin_amdgcn_mfma_f32_16x16x32_bf16(vb, pb.s, oacc[dsub], 0, 0, 0);
      }
    }
    cur ^= 1;
  }

  const float inv = 1.0f / l;
  const int irow = i0 + w * 16 + l15;
  if (MODE == 2) {
#pragma unroll
    for (int dsub = 0; dsub < 8; ++dsub)
#pragma unroll
      for (int r = 0; r < 4; ++r)
        atomicAdd(Op + (size_t)irow * VD + dsub * 16 + g4 * 4 + r,
                  oacc[dsub][r] * inv);
  } else {
    float* op = Op + (size_t)h * (S * VD) + (size_t)irow * VD;
#pragma unroll
    for (int dsub = 0; dsub < 8; ++dsub) {
      float4 v;
      v.x = oacc[dsub][0] * inv;
      v.y = oacc[dsub][1] * inv;
      v.z = oacc[dsub][2] * inv;
      v.w = oacc[dsub][3] * inv;
      *reinterpret_cast<float4*>(op + dsub * 16 + g4 * 4) = v;
    }
  }
}

// Sum the 24 per-head partials into the final (S, 128) output.
__global__ __launch_bounds__(256) void reduce_out_kernel(
    const float* __restrict__ OP, float* __restrict__ out) {
  const int idx = blockIdx.x * 256 + threadIdx.x;
  float s = 0.0f;
#pragma unroll
  for (int hh = 0; hh < NH; ++hh) s += OP[(size_t)hh * (S * VD) + idx];
  out[idx] = s;
}

extern "C" void kernel_launch(void* const* d_in, const int* in_sizes, int n_in,
                              void* d_out, int out_size, void* d_ws, size_t ws_size,
                              hipStream_t stream) {
  const float* nodes = (const float*)d_in[0];
  const float* aux   = (const float*)d_in[1];
  const float* rot   = (const float*)d_in[2];
  const float* Wn    = (const float*)d_in[3];
  const float* bn    = (const float*)d_in[4];
  const float* Wa    = (const float*)d_in[5];
  const float* ba    = (const float*)d_in[6];
  const float* Wr    = (const float*)d_in[7];
  const float* Wv    = (const float*)d_in[8];
  const float* bv    = (const float*)d_in[9];
  float* out = (float*)d_out;

  char* ws = (char*)d_ws;
  const size_t off_conv = 0;                                    // bf16 x 802816
  const size_t off_Kb   = off_conv + (size_t)CONV_TOTAL * 2;
  const size_t off_Qb   = off_Kb + (size_t)S * KQ_STRIDE * 2;
  const size_t off_Vt   = off_Qb + (size_t)S * KQ_STRIDE * 2;
  const size_t off_Gh   = off_Vt + (size_t)NH * VD * S * 2;     // 8*S*32 bf16
  const size_t off_Rh   = off_Gh + (size_t)8 * S * 32 * 2;      // S*32 bf16
  const size_t off_Op   = off_Rh + (size_t)S * 32 * 2;
  const size_t need1    = off_Op + (size_t)NH * S * VD * 4;     // ~46 MB

  bf16* convb = (bf16*)(ws + off_conv);
  bf16* An = convb;
  bf16* Aa = convb + AN_SZ;
  bf16* Bn = convb + AN_SZ + AA_SZ;
  bf16* Ba = convb + AN_SZ + AA_SZ + BN_SZ;
  bf16* Bv = convb + AN_SZ + AA_SZ + BN_SZ + BA_SZ;
  bf16*  Kb = (bf16*)(ws + off_Kb);
  bf16*  Qb = (bf16*)(ws + off_Qb);
  bf16*  Vt = (bf16*)(ws + off_Vt);
  bf16*  Gh = (bf16*)(ws + off_Gh);
  bf16*  Rh = (bf16*)(ws + off_Rh);
  float* Op = (float*)(ws + off_Op);

  convert_kernel<<<CONV_TOTAL / 1024, 256, 0, stream>>>(nodes, aux, Wn, Wa, Wv, convb);
  rotg_kernel<<<S / 32, 256, 0, stream>>>(rot, Wr, Gh, Rh);

  gemm_proj_kernel<128, 0><<<dim3(S / 64, 512 / 64), 256, 0, stream>>>(
      An, Bn, bn, Kb, Qb);
  gemm_proj_kernel<32, 1><<<dim3(S / 64, 512 / 64), 256, 0, stream>>>(
      Aa, Ba, ba, Kb, Qb);
  gemm_proj_kernel<128, 2><<<dim3(S / 64, 3072 / 64), 256, 0, stream>>>(
      An, Bv, bv, Vt, nullptr);

  if (ws_size >= need1) {
    attn_mfma_kernel<1><<<dim3(S / 64, NH), 256, 0, stream>>>(
        Kb, Qb, Vt, Gh, Rh, Op);
    reduce_out_kernel<<<(S * VD) / 256, 256, 0, stream>>>(Op, out);
  } else {
    hipMemsetAsync(d_out, 0, (size_t)out_size * sizeof(float), stream);
    attn_mfma_kernel<2><<<dim3(S / 64, NH), 256, 0, stream>>>(
        Kb, Qb, Vt, Gh, Rh, out);
  }
}

// Round 6
// 115.554 us; speedup vs baseline: 1.3965x; 1.0995x over previous
//
#include <hip/hip_runtime.h>
#include <hip/hip_bf16.h>

// Problem constants
#define S    2048
#define ND   128
#define NA   16
#define H    8
#define C    32
#define NH   24            // 3*H heads total
#define VD   128           // value dim per head
#define KQ_STRIDE (NH*C)   // 768 elems per row of K/Q
#define SCALE 0.3535533905932738f   // 1/sqrt(8)
#define SQS   0.5946035575013605f   // sqrt(SCALE)

// bf16 conversion-buffer element counts (flat regions in ws)
#define AN_SZ (S*ND)        // nodes bf16          262144
#define AA_SZ (S*32)        // aux  bf16 K-pad 32   65536
#define BN_SZ (512*ND)      // Wn   bf16            65536
#define BA_SZ (512*32)      // Wa   bf16 K-pad 32   16384
#define BV_SZ (3072*ND)     // Wv   bf16           393216
#define CONV_TOTAL (AN_SZ + AA_SZ + BN_SZ + BA_SZ + BV_SZ)  // 802816

typedef __attribute__((ext_vector_type(8))) short short8;
typedef __attribute__((ext_vector_type(4))) short s4v;
typedef __attribute__((ext_vector_type(4))) float f32x4;

typedef __hip_bfloat16 bf16;

__device__ __forceinline__ short bf16_bits(float x) {
  bf16 h = __float2bfloat16(x);
  union { bf16 h; short s; } u; u.h = h; return u.s;
}

// ---------------------------------------------------------------------------
// Cast nodes/Wn/Wv to bf16; zero-pad aux/Wa from K=16 to K=32 (exact).
// ---------------------------------------------------------------------------
__global__ __launch_bounds__(256) void convert_kernel(
    const float* __restrict__ nodes, const float* __restrict__ aux,
    const float* __restrict__ Wn, const float* __restrict__ Wa,
    const float* __restrict__ Wv, bf16* __restrict__ out) {
  const int base = (blockIdx.x * 256 + threadIdx.x) * 4;
#pragma unroll
  for (int u = 0; u < 4; ++u) {
    const int idx = base + u;
    int k = idx;
    float v;
    if (k < AN_SZ) {
      v = nodes[k];
    } else if ((k -= AN_SZ) < AA_SZ) {
      const int ccol = k & 31;
      v = (ccol < 16) ? aux[(size_t)(k >> 5) * NA + ccol] : 0.0f;
    } else if ((k -= AA_SZ) < BN_SZ) {
      v = Wn[k];
    } else if ((k -= BN_SZ) < BA_SZ) {
      const int ccol = k & 31;
      v = (ccol < 16) ? Wa[(size_t)(k >> 5) * NA + ccol] : 0.0f;
    } else {
      v = Wv[k - BA_SZ];
    }
    out[idx] = __float2bfloat16(v);
  }
}

// ---------------------------------------------------------------------------
// MFMA projection GEMM. EPI 0: nodes k/q (K scaled by SCALE); 1: aux k/q
// (K scaled); 2: val^T. A rows i, B rows o; D[i][o].
// ---------------------------------------------------------------------------
template <int KE, int EPI>
__global__ __launch_bounds__(256) void gemm_proj_kernel(
    const bf16* __restrict__ A, const bf16* __restrict__ B,
    const float* __restrict__ bias,
    bf16* __restrict__ d0, bf16* __restrict__ d1) {
  const int t = threadIdx.x;
  const int lane = t & 63;
  const int w = t >> 6;
  const int l15 = lane & 15, g4 = lane >> 4;
  const int i0 = blockIdx.x * 64 + w * 16;
  const int o0 = blockIdx.y * 64;

  f32x4 acc[4];
#pragma unroll
  for (int s = 0; s < 4; ++s) acc[s] = (f32x4){0.f, 0.f, 0.f, 0.f};

  const bf16* arow = A + (size_t)(i0 + l15) * KE + g4 * 8;
  const bf16* brow = B + (size_t)(o0 + l15) * KE + g4 * 8;
#pragma unroll
  for (int ks = 0; ks < KE / 32; ++ks) {
    const short8 af = *reinterpret_cast<const short8*>(arow + ks * 32);
#pragma unroll
    for (int s = 0; s < 4; ++s) {
      const short8 bfr = *reinterpret_cast<const short8*>(
          brow + (size_t)s * 16 * KE + ks * 32);
      acc[s] = __builtin_amdgcn_mfma_f32_16x16x32_bf16(af, bfr, acc[s], 0, 0, 0);
    }
  }

#pragma unroll
  for (int s = 0; s < 4; ++s) {
    const int o = o0 + s * 16 + l15;
    const float bb = bias[o];
    if (EPI == 2) {
      s4v pk;
#pragma unroll
      for (int r = 0; r < 4; ++r) pk[r] = bf16_bits(acc[s][r] + bb);
      *reinterpret_cast<s4v*>(d0 + (size_t)o * S + i0 + g4 * 4) = pk;
    } else {
      const int head = (EPI == 0 ? 0 : 8) + (o >> 6);
      const int half = (o >> 5) & 1;
      const int c = o & 31;
      bf16* dst = half ? d1 : d0;
      const float sc = half ? 1.0f : SCALE;  // fold SCALE into K
#pragma unroll
      for (int r = 0; r < 4; ++r)
        dst[(size_t)(i0 + g4 * 4 + r) * KQ_STRIDE + head * C + c] =
            __float2bfloat16((acc[s][r] + bb) * sc);
    }
  }
}

// ---------------------------------------------------------------------------
// Rot-head precompute. M_h = (W_rk_h^T W_rq_h)*sqrt(SCALE); G_i = rot_i^T M_h.
// Emit bf16 hi/lo splits so rot scores run on the SAME MFMA path.
// ---------------------------------------------------------------------------
__global__ __launch_bounds__(256) void rotg_kernel(
    const float* __restrict__ rot, const float* __restrict__ Wr,
    bf16* __restrict__ Ghat, bf16* __restrict__ Rhat) {
  __shared__ float M[8][4][4];
  const int t = threadIdx.x;
  if (t < 128) {
    const int hl = t >> 4, a = (t >> 2) & 3, b = t & 3;
    float s = 0.0f;
#pragma unroll
    for (int c = 0; c < 32; ++c)
      s += Wr[(size_t)(hl * 64 + c) * 4 + a] * Wr[(size_t)(hl * 64 + 32 + c) * 4 + b];
    M[hl][a][b] = s * SQS;
  }
  __syncthreads();
  const int i  = blockIdx.x * 32 + (t >> 3);
  const int hl = t & 7;
  const float4 rv = *reinterpret_cast<const float4*>(rot + (size_t)i * 4);
  float g[4];
#pragma unroll
  for (int b = 0; b < 4; ++b)
    g[b] = rv.x * M[hl][0][b] + rv.y * M[hl][1][b]
         + rv.z * M[hl][2][b] + rv.w * M[hl][3][b];

  short hi[4], lo[4];
#pragma unroll
  for (int b = 0; b < 4; ++b) {
    bf16 hb = __float2bfloat16(g[b]);
    hi[b] = bf16_bits(g[b]);
    lo[b] = bf16_bits(g[b] - __bfloat162float(hb));
  }
  const short8 zz = {0, 0, 0, 0, 0, 0, 0, 0};
  short8 w0 = {hi[0], hi[1], hi[2], hi[3], lo[0], lo[1], lo[2], lo[3]};
  short8 w1 = {hi[0], hi[1], hi[2], hi[3], 0, 0, 0, 0};
  bf16* gp = Ghat + ((size_t)hl * S + i) * 32;
  *reinterpret_cast<short8*>(gp)      = w0;
  *reinterpret_cast<short8*>(gp + 8)  = w1;
  *reinterpret_cast<short8*>(gp + 16) = zz;
  *reinterpret_cast<short8*>(gp + 24) = zz;

  if (hl == 0) {
    float rr[4] = {rv.x, rv.y, rv.z, rv.w};
    short rh[4], rl[4];
#pragma unroll
    for (int b = 0; b < 4; ++b) {
      bf16 hb = __float2bfloat16(rr[b]);
      rh[b] = bf16_bits(rr[b]);
      rl[b] = bf16_bits(rr[b] - __bfloat162float(hb));
    }
    short8 r0 = {rh[0], rh[1], rh[2], rh[3], rh[0], rh[1], rh[2], rh[3]};
    short8 r1 = {rl[0], rl[1], rl[2], rl[3], 0, 0, 0, 0};
    bf16* rp = Rhat + (size_t)i * 32;
    *reinterpret_cast<short8*>(rp)      = r0;
    *reinterpret_cast<short8*>(rp + 8)  = r1;
    *reinterpret_cast<short8*>(rp + 16) = zz;
    *reinterpret_cast<short8*>(rp + 24) = zz;
  }
}

// ---------------------------------------------------------------------------
// Swapped-layout MFMA flash attention, 2-tile unrolled.
// Static Vs0/Vs1 buffers -> all LDS addresses are base-VGPR + immediate.
// Q fragments prefetched one tile ahead (qA/qB). setprio around MFMA.
// MODE 1: per-head O to Op (reduce later). MODE 2: atomicAdd into out.
// ---------------------------------------------------------------------------
template <int MODE>
__global__ __launch_bounds__(256, 3) void attn_mfma_kernel(
    const bf16* __restrict__ Kb, const bf16* __restrict__ Qb,
    const bf16* __restrict__ Vt, const bf16* __restrict__ Ghat,
    const bf16* __restrict__ Rhat, float* __restrict__ Op) {
  const int h    = blockIdx.y;
  const int i0   = blockIdx.x * 64;
  const int t    = threadIdx.x;
  const int lane = t & 63;
  const int w    = t >> 6;
  const int l15  = lane & 15;
  const int g4   = lane >> 4;
  const bool isrot = (h >= 16);

  __shared__ __align__(16) bf16 Vs0[128 * 64];            // 16 KB each
  __shared__ __align__(16) bf16 Vs1[128 * 64];
  __shared__ __align__(16) unsigned int Ps[4][16][40];    // 10 KB

  const bf16* kp; const bf16* qp; int kst, qst;
  if (!isrot) {
    kp = Kb + h * C; qp = Qb + h * C; kst = KQ_STRIDE; qst = KQ_STRIDE;
  } else {
    kp = Ghat + (size_t)(h - 16) * S * 32; qp = Rhat; kst = 32; qst = 32;
  }

  // B-frag: K row for this wave's i = i0 + w*16 + l15 (loop-invariant)
  const short8 kfrag = *reinterpret_cast<const short8*>(
      kp + (size_t)(i0 + w * 16 + l15) * kst + g4 * 8);

  float m = -1e30f, l = 0.0f;
  f32x4 oacc[8];
#pragma unroll
  for (int d = 0; d < 8; ++d) oacc[d] = (f32x4){0.f, 0.f, 0.f, 0.f};

  // ---- thread-constant LDS offsets ----
  // V stage: thread owns (row vd = t>>1, 32-elem half vjh)
  const int vd  = t >> 1;
  const int vjh4 = (t & 1) * 4;  // (vjh/8)
  const int wo0 = vd * 64 + (((vjh4 + 0) ^ (vd & 7)) << 3);
  const int wo1 = vd * 64 + (((vjh4 + 1) ^ (vd & 7)) << 3);
  const int wo2 = vd * 64 + (((vjh4 + 2) ^ (vd & 7)) << 3);
  const int wo3 = vd * 64 + (((vjh4 + 3) ^ (vd & 7)) << 3);
  // PV V-read bases (kh = 0,1); dsub handled by +dsub*1024 immediate
  const int vbase0 = l15 * 64 + (((g4 + 0) ^ (l15 & 7)) << 3);
  const int vbase1 = l15 * 64 + (((g4 + 4) ^ (l15 & 7)) << 3);

  const bf16* vsrc = Vt + ((size_t)h * VD + vd) * S + (t & 1) * 32;
  short8 vr0, vr1, vr2, vr3;
  short8 qA0, qA1, qA2, qA3, qB0, qB1, qB2, qB3;

  // ---- prologue: V(0)->Vs0, V(1)->regs, Q(0)->qA ----
  vr0 = *reinterpret_cast<const short8*>(vsrc);
  vr1 = *reinterpret_cast<const short8*>(vsrc + 8);
  vr2 = *reinterpret_cast<const short8*>(vsrc + 16);
  vr3 = *reinterpret_cast<const short8*>(vsrc + 24);
  *reinterpret_cast<short8*>(&Vs0[wo0]) = vr0;
  *reinterpret_cast<short8*>(&Vs0[wo1]) = vr1;
  *reinterpret_cast<short8*>(&Vs0[wo2]) = vr2;
  *reinterpret_cast<short8*>(&Vs0[wo3]) = vr3;
  vr0 = *reinterpret_cast<const short8*>(vsrc + 64);
  vr1 = *reinterpret_cast<const short8*>(vsrc + 72);
  vr2 = *reinterpret_cast<const short8*>(vsrc + 80);
  vr3 = *reinterpret_cast<const short8*>(vsrc + 88);
  {
    const bf16* qn = qp + (size_t)l15 * qst + g4 * 8;
    qA0 = *reinterpret_cast<const short8*>(qn);
    qA1 = *reinterpret_cast<const short8*>(qn + 16 * qst);
    qA2 = *reinterpret_cast<const short8*>(qn + 32 * qst);
    qA3 = *reinterpret_cast<const short8*>(qn + 48 * qst);
  }

#define TILE_BODY(VB_CUR, VB_NXT, Q0, Q1, Q2, Q3, QN0, QN1, QN2, QN3, J0)     \
  {                                                                           \
    __syncthreads();                                                          \
    if ((J0) + 64 < S) {                                                      \
      *reinterpret_cast<short8*>(&VB_NXT[wo0]) = vr0;                         \
      *reinterpret_cast<short8*>(&VB_NXT[wo1]) = vr1;                         \
      *reinterpret_cast<short8*>(&VB_NXT[wo2]) = vr2;                         \
      *reinterpret_cast<short8*>(&VB_NXT[wo3]) = vr3;                         \
      if ((J0) + 128 < S) {                                                   \
        const bf16* p = vsrc + (J0) + 128;                                    \
        vr0 = *reinterpret_cast<const short8*>(p);                            \
        vr1 = *reinterpret_cast<const short8*>(p + 8);                        \
        vr2 = *reinterpret_cast<const short8*>(p + 16);                       \
        vr3 = *reinterpret_cast<const short8*>(p + 24);                       \
      }                                                                       \
      const bf16* qn = qp + (size_t)((J0) + 64 + l15) * qst + g4 * 8;         \
      QN0 = *reinterpret_cast<const short8*>(qn);                             \
      QN1 = *reinterpret_cast<const short8*>(qn + 16 * qst);                  \
      QN2 = *reinterpret_cast<const short8*>(qn + 32 * qst);                  \
      QN3 = *reinterpret_cast<const short8*>(qn + 48 * qst);                  \
    }                                                                         \
    f32x4 sf[4];                                                              \
    {                                                                         \
      const f32x4 z = {0.f, 0.f, 0.f, 0.f};                                   \
      __builtin_amdgcn_s_setprio(1);                                          \
      sf[0] = __builtin_amdgcn_mfma_f32_16x16x32_bf16(Q0, kfrag, z, 0, 0, 0); \
      sf[1] = __builtin_amdgcn_mfma_f32_16x16x32_bf16(Q1, kfrag, z, 0, 0, 0); \
      sf[2] = __builtin_amdgcn_mfma_f32_16x16x32_bf16(Q2, kfrag, z, 0, 0, 0); \
      sf[3] = __builtin_amdgcn_mfma_f32_16x16x32_bf16(Q3, kfrag, z, 0, 0, 0); \
      __builtin_amdgcn_s_setprio(0);                                          \
    }                                                                         \
    if (isrot) {                                                              \
      _Pragma("unroll") for (int sub = 0; sub < 4; ++sub)                     \
          _Pragma("unroll") for (int r = 0; r < 4; ++r)                       \
              sf[sub][r] *= sf[sub][r];                                       \
    }                                                                         \
    float tm = sf[0][0];                                                      \
    _Pragma("unroll") for (int sub = 0; sub < 4; ++sub)                       \
        _Pragma("unroll") for (int r = 0; r < 4; ++r)                         \
            tm = fmaxf(tm, sf[sub][r]);                                       \
    tm = fmaxf(tm, __shfl_xor(tm, 16));                                       \
    tm = fmaxf(tm, __shfl_xor(tm, 32));                                       \
    if (__any(tm > m)) {                                                      \
      const float mnew = fmaxf(m, tm);                                        \
      const float corr = __expf(m - mnew);                                    \
      m = mnew;                                                               \
      l *= corr;                                                              \
      _Pragma("unroll") for (int d = 0; d < 8; ++d)                           \
          _Pragma("unroll") for (int r = 0; r < 4; ++r)                       \
              oacc[d][r] *= corr;                                             \
    }                                                                         \
    float ls = 0.0f;                                                          \
    _Pragma("unroll") for (int sub = 0; sub < 4; ++sub)                       \
        _Pragma("unroll") for (int r = 0; r < 4; ++r) {                       \
          const float p = __expf(sf[sub][r] - m);                             \
          sf[sub][r] = p;                                                     \
          ls += p;                                                            \
        }                                                                     \
    ls += __shfl_xor(ls, 16);                                                 \
    ls += __shfl_xor(ls, 32);                                                 \
    l += ls;                                                                  \
    _Pragma("unroll") for (int sub = 0; sub < 4; ++sub) {                     \
      unsigned int u0, u1;                                                    \
      asm volatile("v_cvt_pk_bf16_f32 %0, %1, %2"                             \
                   : "=v"(u0) : "v"(sf[sub][0]), "v"(sf[sub][1]));            \
      asm volatile("v_cvt_pk_bf16_f32 %0, %1, %2"                             \
                   : "=v"(u1) : "v"(sf[sub][2]), "v"(sf[sub][3]));            \
      uint2 pk; pk.x = u0; pk.y = u1;                                         \
      *reinterpret_cast<uint2*>(&Ps[w][l15][sub * 8 + g4 * 2]) = pk;          \
    }                                                                         \
    {                                                                         \
      union { uint4 u; short8 s; } pb0, pb1;                                  \
      pb0.u = *reinterpret_cast<const uint4*>(&Ps[w][l15][g4 * 4]);           \
      pb1.u = *reinterpret_cast<const uint4*>(&Ps[w][l15][16 + g4 * 4]);      \
      __builtin_amdgcn_s_setprio(1);                                          \
      _Pragma("unroll") for (int dsub = 0; dsub < 8; ++dsub) {                \
        const short8 vb = *reinterpret_cast<const short8*>(                   \
            &VB_CUR[vbase0 + dsub * 1024]);                                   \
        oacc[dsub] =                                                          \
            __builtin_amdgcn_mfma_f32_16x16x32_bf16(vb, pb0.s, oacc[dsub], 0, 0, 0); \
      }                                                                       \
      _Pragma("unroll") for (int dsub = 0; dsub < 8; ++dsub) {                \
        const short8 vb = *reinterpret_cast<const short8*>(                   \
            &VB_CUR[vbase1 + dsub * 1024]);                                   \
        oacc[dsub] =                                                          \
            __builtin_amdgcn_mfma_f32_16x16x32_bf16(vb, pb1.s, oacc[dsub], 0, 0, 0); \
      }                                                                       \
      __builtin_amdgcn_s_setprio(0);                                          \
    }                                                                         \
  }

  for (int j0 = 0; j0 < S; j0 += 128) {
    TILE_BODY(Vs0, Vs1, qA0, qA1, qA2, qA3, qB0, qB1, qB2, qB3, j0);
    TILE_BODY(Vs1, Vs0, qB0, qB1, qB2, qB3, qA0, qA1, qA2, qA3, j0 + 64);
  }
#undef TILE_BODY

  const float inv = 1.0f / l;
  const int irow = i0 + w * 16 + l15;
  if (MODE == 2) {
#pragma unroll
    for (int dsub = 0; dsub < 8; ++dsub)
#pragma unroll
      for (int r = 0; r < 4; ++r)
        atomicAdd(Op + (size_t)irow * VD + dsub * 16 + g4 * 4 + r,
                  oacc[dsub][r] * inv);
  } else {
    float* op = Op + (size_t)h * (S * VD) + (size_t)irow * VD;
#pragma unroll
    for (int dsub = 0; dsub < 8; ++dsub) {
      float4 v;
      v.x = oacc[dsub][0] * inv;
      v.y = oacc[dsub][1] * inv;
      v.z = oacc[dsub][2] * inv;
      v.w = oacc[dsub][3] * inv;
      *reinterpret_cast<float4*>(op + dsub * 16 + g4 * 4) = v;
    }
  }
}

// Sum the 24 per-head partials into the final (S, 128) output.
__global__ __launch_bounds__(256) void reduce_out_kernel(
    const float* __restrict__ OP, float* __restrict__ out) {
  const int idx = blockIdx.x * 256 + threadIdx.x;
  float s = 0.0f;
#pragma unroll
  for (int hh = 0; hh < NH; ++hh) s += OP[(size_t)hh * (S * VD) + idx];
  out[idx] = s;
}

extern "C" void kernel_launch(void* const* d_in, const int* in_sizes, int n_in,
                              void* d_out, int out_size, void* d_ws, size_t ws_size,
                              hipStream_t stream) {
  const float* nodes = (const float*)d_in[0];
  const float* aux   = (const float*)d_in[1];
  const float* rot   = (const float*)d_in[2];
  const float* Wn    = (const float*)d_in[3];
  const float* bn    = (const float*)d_in[4];
  const float* Wa    = (const float*)d_in[5];
  const float* ba    = (const float*)d_in[6];
  const float* Wr    = (const float*)d_in[7];
  const float* Wv    = (const float*)d_in[8];
  const float* bv    = (const float*)d_in[9];
  float* out = (float*)d_out;

  char* ws = (char*)d_ws;
  const size_t off_conv = 0;                                    // bf16 x 802816
  const size_t off_Kb   = off_conv + (size_t)CONV_TOTAL * 2;
  const size_t off_Qb   = off_Kb + (size_t)S * KQ_STRIDE * 2;
  const size_t off_Vt   = off_Qb + (size_t)S * KQ_STRIDE * 2;
  const size_t off_Gh   = off_Vt + (size_t)NH * VD * S * 2;     // 8*S*32 bf16
  const size_t off_Rh   = off_Gh + (size_t)8 * S * 32 * 2;      // S*32 bf16
  const size_t off_Op   = off_Rh + (size_t)S * 32 * 2;
  const size_t need1    = off_Op + (size_t)NH * S * VD * 4;     // ~46 MB

  bf16* convb = (bf16*)(ws + off_conv);
  bf16* An = convb;
  bf16* Aa = convb + AN_SZ;
  bf16* Bn = convb + AN_SZ + AA_SZ;
  bf16* Ba = convb + AN_SZ + AA_SZ + BN_SZ;
  bf16* Bv = convb + AN_SZ + AA_SZ + BN_SZ + BA_SZ;
  bf16*  Kb = (bf16*)(ws + off_Kb);
  bf16*  Qb = (bf16*)(ws + off_Qb);
  bf16*  Vt = (bf16*)(ws + off_Vt);
  bf16*  Gh = (bf16*)(ws + off_Gh);
  bf16*  Rh = (bf16*)(ws + off_Rh);
  float* Op = (float*)(ws + off_Op);

  convert_kernel<<<CONV_TOTAL / 1024, 256, 0, stream>>>(nodes, aux, Wn, Wa, Wv, convb);
  rotg_kernel<<<S / 32, 256, 0, stream>>>(rot, Wr, Gh, Rh);

  gemm_proj_kernel<128, 0><<<dim3(S / 64, 512 / 64), 256, 0, stream>>>(
      An, Bn, bn, Kb, Qb);
  gemm_proj_kernel<32, 1><<<dim3(S / 64, 512 / 64), 256, 0, stream>>>(
      Aa, Ba, ba, Kb, Qb);
  gemm_proj_kernel<128, 2><<<dim3(S / 64, 3072 / 64), 256, 0, stream>>>(
      An, Bv, bv, Vt, nullptr);

  if (ws_size >= need1) {
    attn_mfma_kernel<1><<<dim3(S / 64, NH), 256, 0, stream>>>(
        Kb, Qb, Vt, Gh, Rh, Op);
    reduce_out_kernel<<<(S * VD) / 256, 256, 0, stream>>>(Op, out);
  } else {
    hipMemsetAsync(d_out, 0, (size_t)out_size * sizeof(float), stream);
    attn_mfma_kernel<2><<<dim3(S / 64, NH), 256, 0, stream>>>(
        Kb, Qb, Vt, Gh, Rh, out);
  }
}